// Round 10
// baseline (193.356 us; speedup 1.0000x reference)
//
#include <hip/hip_runtime.h>
#include <math.h>

// Tropical (max-plus) depthwise 3x3 conv, stride=1, pad=1, dil=1.
// x: (B=8, C=64, H=224, W=224) fp32; kernel: (64,1,3,3) fp32; out = x shape.
//
// R11: copy-homomorphic streaming stencil. Six prior variants (batch-MLP,
// rolling-window, wave-strip+shuffle, NT stores, XCD swizzle) all plateau
// at 59-68us / ~2.5 TB/s with NO saturated pipe, while the same machine
// runs fills at 6.9 and copies at 6.3 TB/s. Shared flaw: phase-oscillation
// (vmcnt(0) batch-wait -> all-compute -> all-store). This kernel streams:
// one WAVE walks 16 consecutive rows of a plane with a 4-slot register
// ring; per row: {issue load r+2 | arrival-process r+1 (shuffle halos,
// waits only that row) | compute+store r}. One 896B load + one 896B store
// per row, perfectly sequential per wave, demand smoothed, compute always
// overlaps in-flight loads. sched_barrier(0) pins each issue above the
// compute so the scheduler can't sink the prefetch.
//   - lanes 0..55 one float4 each (full 224-wide row); 56..63 clamped
//     duplicates, masked at store; halos via __shfl_up/__shfl_down.
//   - 7168 waves / 1792 blocks = 8 x 224 (bijective XCD swizzle).

#define H_DIM 224
#define W_DIM 224
#define SR    16            // rows per wave strip
#define SPP   14            // strips per plane (224/16)
#define C_DIM 64

__global__ __launch_bounds__(256) void tropical_conv_kernel(
    const float* __restrict__ x,
    const float* __restrict__ kern,
    float* __restrict__ out)
{
    int bid  = blockIdx.x;
    int cpx  = gridDim.x >> 3;                 // 224
    int swz  = (bid & 7) * cpx + (bid >> 3);   // bijective: 1792 = 8*224
    int lane = threadIdx.x & 63;
    int wid  = swz * 4 + (threadIdx.x >> 6);   // 0..7167

    int s  = wid % SPP;          // strip within plane
    int bc = wid / SPP;          // fused batch*channel plane
    int c  = bc & (C_DIM - 1);

    const float* kc = kern + c * 9;
    float k00 = kc[0], k01 = kc[1], k02 = kc[2];
    float k10 = kc[3], k11 = kc[4], k12 = kc[5];
    float k20 = kc[6], k21 = kc[7], k22 = kc[8];

    const float NEG = -INFINITY;

    const float* plane  = x   + (size_t)bc * (H_DIM * W_DIM);
    float*       oplane = out + (size_t)bc * (H_DIM * W_DIM);

    int i0  = s * SR;
    int cl  = (lane < 56) ? lane : 55;     // clamped column slot
    int col = cl * 4;

    // Ring: input row r = i0-1+k lives in slot k&3.
    float4 rv[4];
    float  lf[4], rg[4];

    // Issue load of ring row k (clamped address; dead rows fixed at ARRIVE).
#define ISSUE(k) do {                                                        \
        int _r  = i0 - 1 + (k);                                              \
        int _rc = _r < 0 ? 0 : (_r > H_DIM - 1 ? H_DIM - 1 : _r);            \
        rv[(k) & 3] = *(const float4*)(plane + (size_t)_rc * W_DIM + col);   \
    } while (0)

    // Arrival processing of ring row k: shuffle halos + dead-row select.
    // The shuffle forces the wait for THIS row only (younger loads stay
    // in flight -> compiler emits a counted vmcnt, not vmcnt(0)).
#define ARRIVE(k, dead) do {                                                 \
        int   _sl = (k) & 3;                                                 \
        float4 _v = rv[_sl];                                                 \
        float _up = __shfl_up(_v.w, 1);                                      \
        float _dn = __shfl_down(_v.x, 1);                                    \
        bool  _d  = (dead);                                                  \
        _v.x = _d ? NEG : _v.x;                                              \
        _v.y = _d ? NEG : _v.y;                                              \
        _v.z = _d ? NEG : _v.z;                                              \
        _v.w = _d ? NEG : _v.w;                                              \
        rv[_sl] = _v;                                                        \
        lf[_sl] = (_d || lane == 0)  ? NEG : _up;                            \
        rg[_sl] = (_d || lane >= 55) ? NEG : _dn;                            \
    } while (0)

    // Prologue: rows k=0,1 resident, k=2 in flight.
    ISSUE(0); ISSUE(1); ISSUE(2);
    __builtin_amdgcn_sched_barrier(0);
    ARRIVE(0, s == 0);          // row -1 is the tropical pad
    ARRIVE(1, false);

    #pragma unroll
    for (int o = 0; o < SR; ++o) {
        if (o + 3 <= SR + 1) {           // k range 3..17
            ISSUE(o + 3);                // prefetch for iteration o+1
        }
        __builtin_amdgcn_sched_barrier(0);   // pin: issue stays above compute
        ARRIVE(o + 2, (s == SPP - 1) && (o + 2 == SR + 1));  // row 224 pad

        // Compute output row i0+o from ring rows k=o, o+1, o+2.
        float4 acc = make_float4(NEG, NEG, NEG, NEG);
        #pragma unroll
        for (int ki = 0; ki < 3; ++ki) {
            int sl = (o + ki) & 3;       // compile-time after unroll
            float t0 = (ki == 0) ? k00 : (ki == 1) ? k10 : k20;
            float t1 = (ki == 0) ? k01 : (ki == 1) ? k11 : k21;
            float t2 = (ki == 0) ? k02 : (ki == 1) ? k12 : k22;
            float4 a = rv[sl];
            acc.x = fmaxf(acc.x, fmaxf(fmaxf(lf[sl] + t0, a.x + t1), a.y    + t2));
            acc.y = fmaxf(acc.y, fmaxf(fmaxf(a.x    + t0, a.y + t1), a.z    + t2));
            acc.z = fmaxf(acc.z, fmaxf(fmaxf(a.y    + t0, a.z + t1), a.w    + t2));
            acc.w = fmaxf(acc.w, fmaxf(fmaxf(a.z    + t0, a.w + t1), rg[sl] + t2));
        }
        if (lane < 56) {
            *(float4*)(oplane + (size_t)(i0 + o) * W_DIM + col) = acc;
        }
    }
#undef ISSUE
#undef ARRIVE
}

extern "C" void kernel_launch(void* const* d_in, const int* in_sizes, int n_in,
                              void* d_out, int out_size, void* d_ws, size_t ws_size,
                              hipStream_t stream) {
    const float* x    = (const float*)d_in[0];
    const float* kern = (const float*)d_in[1];
    float* out        = (float*)d_out;

    // waves = B*C*SPP = 8*64*14 = 7168 ; 4 waves/block -> 1792 blocks.
    const int grid  = 8 * C_DIM * SPP / 4;
    const int block = 256;
    tropical_conv_kernel<<<grid, block, 0, stream>>>(x, kern, out);
}

// Round 11
// 186.398 us; speedup vs baseline: 1.0373x; 1.0373x over previous
//
#include <hip/hip_runtime.h>
#include <math.h>

// Tropical (max-plus) depthwise 3x3 conv, stride=1, pad=1, dil=1.
// x: (B=8, C=64, H=224, W=224) fp32; kernel: (64,1,3,3) fp32; out = x shape.
//
// R12 = R8 verbatim — the best-measured variant (61.0us dispatch, 185.4us
// bench). Final revert: eight structural variants (batch-MLP, rolling
// window, branch-free clamp, wave-strip+shuffle, NT stores, streaming
// ring) all plateau at 60-68us / ~2.5 TB/s with no saturated pipe;
// the plateau is pattern-independent, so keep the simplest/fastest.
//
// R8 structure:
//   - one WAVE owns a 4-output-row x full-width strip; lanes 0..55 each
//     hold one float4 of a row (56*4 = 224); lanes 56..63 are clamped
//     duplicates (same cache lines, no extra traffic, masked on store);
//   - halos via __shfl_up/__shfl_down, no scalar gathers: 6 VMEM loads
//     per strip, each a single contiguous 896B wave-aligned burst;
//   - sched_barrier(0) pins the 6-load cluster;
//   - 28,672 waves, VGPR=32 -> occupancy ~65%;
//   - bijective XCD swizzle (grid 7168 = 8 x 896).

#define H_DIM 224
#define W_DIM 224
#define SR    4             // output rows per wave strip
#define SPP   56            // strips per plane (224/4)
#define C_DIM 64
#define NXCD  8

__global__ __launch_bounds__(256) void tropical_conv_kernel(
    const float* __restrict__ x,
    const float* __restrict__ kern,
    float* __restrict__ out)
{
    // Bijective XCD swizzle: grid 7168 = 8 x 896.
    int bid  = blockIdx.x;
    int cpx  = gridDim.x >> 3;
    int swz  = (bid & (NXCD - 1)) * cpx + (bid >> 3);

    int lane = threadIdx.x & 63;
    int wid  = swz * 4 + (threadIdx.x >> 6);   // global wave id, 0..28671

    int s  = wid % SPP;          // strip within plane
    int bc = wid / SPP;          // fused batch*channel plane
    int c  = bc & (C_DIM - 1);

    const float* kc = kern + c * 9;
    float k00 = kc[0], k01 = kc[1], k02 = kc[2];
    float k10 = kc[3], k11 = kc[4], k12 = kc[5];
    float k20 = kc[6], k21 = kc[7], k22 = kc[8];

    const float NEG = -INFINITY;

    const float* plane  = x   + (size_t)bc * (H_DIM * W_DIM);
    float*       oplane = out + (size_t)bc * (H_DIM * W_DIM);

    int i0  = s * SR;
    int cl  = (lane < 56) ? lane : 55;     // clamped column slot
    int col = cl * 4;

    // ---- 6 contiguous wave-aligned loads (rows i0-1 .. i0+4, clamped) ----
    float4 rv[SR + 2];
    #pragma unroll
    for (int rr = 0; rr < SR + 2; ++rr) {
        int r  = i0 - 1 + rr;
        int rc = r < 0 ? 0 : (r > H_DIM - 1 ? H_DIM - 1 : r);
        rv[rr] = *(const float4*)(plane + (size_t)rc * W_DIM + col);
    }
    __builtin_amdgcn_sched_barrier(0);   // pin: all 6 loads issue first

    // ---- dead-row fixup (rows -1 / 224 -> tropical neutral) ----
    bool top = (s == 0);
    bool bot = (s == SPP - 1);
    rv[0].x = top ? NEG : rv[0].x;
    rv[0].y = top ? NEG : rv[0].y;
    rv[0].z = top ? NEG : rv[0].z;
    rv[0].w = top ? NEG : rv[0].w;
    rv[SR + 1].x = bot ? NEG : rv[SR + 1].x;
    rv[SR + 1].y = bot ? NEG : rv[SR + 1].y;
    rv[SR + 1].z = bot ? NEG : rv[SR + 1].z;
    rv[SR + 1].w = bot ? NEG : rv[SR + 1].w;

    // ---- halos via cross-lane shuffle (no memory) ----
    float lf[SR + 2], rg[SR + 2];
    #pragma unroll
    for (int rr = 0; rr < SR + 2; ++rr) {
        float up = __shfl_up(rv[rr].w, 1);     // lane-1's last element
        float dn = __shfl_down(rv[rr].x, 1);   // lane+1's first element
        lf[rr] = (lane > 0)  ? up : NEG;       // lane 0 = left pad
        rg[rr] = (lane < 55) ? dn : NEG;       // lane 55 = right pad
    }

    // ---- compute 4 output rows ----
    #pragma unroll
    for (int o = 0; o < SR; ++o) {
        float4 acc = make_float4(NEG, NEG, NEG, NEG);
        #pragma unroll
        for (int ki = 0; ki < 3; ++ki) {
            int rr = o + ki;            // compile-time constant after unroll
            float t0 = (ki == 0) ? k00 : (ki == 1) ? k10 : k20;
            float t1 = (ki == 0) ? k01 : (ki == 1) ? k11 : k21;
            float t2 = (ki == 0) ? k02 : (ki == 1) ? k12 : k22;
            float4 a = rv[rr];
            acc.x = fmaxf(acc.x, fmaxf(fmaxf(lf[rr] + t0, a.x + t1), a.y    + t2));
            acc.y = fmaxf(acc.y, fmaxf(fmaxf(a.x    + t0, a.y + t1), a.z    + t2));
            acc.z = fmaxf(acc.z, fmaxf(fmaxf(a.y    + t0, a.z + t1), a.w    + t2));
            acc.w = fmaxf(acc.w, fmaxf(fmaxf(a.z    + t0, a.w + t1), rg[rr] + t2));
        }
        if (lane < 56) {
            *(float4*)(oplane + (size_t)(i0 + o) * W_DIM + col) = acc;
        }
    }
}

extern "C" void kernel_launch(void* const* d_in, const int* in_sizes, int n_in,
                              void* d_out, int out_size, void* d_ws, size_t ws_size,
                              hipStream_t stream) {
    const float* x    = (const float*)d_in[0];
    const float* kern = (const float*)d_in[1];
    float* out        = (float*)d_out;

    // waves = B*C*SPP = 8*64*56 = 28,672 ; 4 waves/block -> 7168 blocks.
    const int grid  = 8 * C_DIM * SPP / 4;
    const int block = 256;
    tropical_conv_kernel<<<grid, block, 0, stream>>>(x, kern, out);
}